// Round 9
// baseline (262.496 us; speedup 1.0000x reference)
//
#include <hip/hip_runtime.h>

#define BB 8
#define SS 4096
#define DD 128

typedef __attribute__((ext_vector_type(8))) short v8s;
typedef __attribute__((ext_vector_type(4))) float v4f;
typedef __attribute__((ext_vector_type(16))) float v16f;

__device__ __forceinline__ unsigned short f2bf(float f) {
    unsigned int u = __float_as_uint(f);
    u += 0x7fffu + ((u >> 16) & 1u);
    return (unsigned short)(u >> 16);
}
// pack bf16(a) | bf16(b)<<16, round-half-up, via v_perm
__device__ __forceinline__ unsigned int pk_bf16(float a, float b) {
    unsigned int ua = __float_as_uint(a) + 0x8000u;
    unsigned int ub = __float_as_uint(b) + 0x8000u;
    return __builtin_amdgcn_perm(ub, ua, 0x07060302u);
}

#if !defined(__HIP_DEVICE_COMPILE__)
#define MFMA16(a, b, c) (c)
#define MFMA32(a, b, c) (c)
#else
#define MFMA16(a, b, c) __builtin_amdgcn_mfma_f32_16x16x32_bf16((a), (b), (c), 0, 0, 0)
#define MFMA32(a, b, c) __builtin_amdgcn_mfma_f32_32x32x16_bf16((a), (b), (c), 0, 0, 0)
#endif

#if !defined(__HIP_DEVICE_COMPILE__)
#define EXP2F(x) exp2f(x)
#elif __has_builtin(__builtin_amdgcn_exp2f)
#define EXP2F(x) __builtin_amdgcn_exp2f(x)
#else
#define EXP2F(x) exp2f(x)
#endif

// (1/sqrt(128)) * log2(e): softmax in 2^x domain (no max subtraction: scores
// in log2 domain ~N(0,~6^2), fp32 overflow needs >20 sigma; the uniform
// scale cancels exactly in O/l). Both K-halves share the scale -> merging
// partial O/l is a plain add.
#define QSCALE 0.12751743f

// ---------------- kernel 0: W transpose (r6-verified verbatim) -------------
__global__ __launch_bounds__(256) void prep_kernel(
    const float* __restrict__ Wq, const float* __restrict__ Wk,
    const float* __restrict__ Wv, unsigned short* __restrict__ Wt)
{
    int id = blockIdx.x * 256 + threadIdx.x;
    int w = id >> 14;
    int n = (id >> 7) & 127;
    int k = id & 127;
    const float* W = (w == 0) ? Wq : (w == 1) ? Wk : Wv;
    Wt[id] = f2bf(W[k * 128 + n]);
}

// ---------------- kernel 1: projections, ALL 3 matrices per block ----------
// r8-verified compute (x + trig once for 3 matrices). NEW: K and V are
// written to global in MFMA-FRAGMENT ORDER so flash can load operands
// straight global->register with fully coalesced dwordx4:
//   kF[b][t(32-key tile)][c=d>>3][key&31][8 d-elems]   (natural key order)
//   vF[b][t][c=key-octet(frag order)][d 0..127][8 key-elems] (quadp order)
__global__ __launch_bounds__(256, 2) void proj_kernel(
    const float* __restrict__ x, const unsigned short* __restrict__ Wt,
    const float* __restrict__ bq, const float* __restrict__ bk,
    const float* __restrict__ bv,
    unsigned short* __restrict__ qo, unsigned short* __restrict__ kF,
    unsigned short* __restrict__ vF)
{
    __shared__ __attribute__((aligned(16))) unsigned short w_lds[128 * 136]; // 34816 B
    __shared__ __attribute__((aligned(16))) unsigned short o_lds[9216];      // 18432 B

    const int tid = threadIdx.x;
    const int wave = tid >> 6;
    const int lane = tid & 63;
    const int quad = lane >> 4;
    const int l15 = lane & 15;
    const int rbase = blockIdx.x * 64;

    const int flatrow = rbase + wave * 16 + l15;
    const int srow = flatrow & 4095;
    v8s af[4];
#pragma unroll
    for (int kc = 0; kc < 4; ++kc) {
        const int kbase = kc * 32 + quad * 8;
        const v4f* xp = (const v4f*)(x + (size_t)flatrow * DD + kbase);
        v4f x0 = xp[0], x1 = xp[1];
        float p[8];
#pragma unroll
        for (int j = 0; j < 8; j += 2) {
            float freq = __expf((float)(kbase + j) * -0.07195578415606394f);
            float arg = (float)srow * freq;
            p[j] = __sinf(arg);
            p[j + 1] = __cosf(arg);
        }
        v8s a;
#pragma unroll
        for (int j = 0; j < 4; ++j) a[j] = (short)f2bf(x0[j] + p[j]);
#pragma unroll
        for (int j = 0; j < 4; ++j) a[4 + j] = (short)f2bf(x1[j] + p[4 + j]);
        af[kc] = a;
    }

    const int quadp = ((quad & 1) << 1) | (quad >> 1);
    const int b0 = rbase >> 12, s0 = rbase & 4095;
    const size_t t0 = (size_t)b0 * 128 + (s0 >> 5);   // 32-key tile index

#pragma unroll 1
    for (int m = 0; m < 3; ++m) {
        const float* bias = (m == 0) ? bq : (m == 1) ? bk : bv;
        __syncthreads();   // previous m's users of w_lds/o_lds done
        const unsigned short* Wp = Wt + (m << 14);
#pragma unroll
        for (int it = 0; it < 8; ++it) {
            int id = it * 256 + tid;
            int n = id >> 4, c8 = id & 15;
            *(v8s*)(w_lds + n * 136 + c8 * 8) = *(const v8s*)(Wp + n * 128 + c8 * 8);
        }
        __syncthreads();   // w_lds ready

#pragma unroll
        for (int nb = 0; nb < 8; ++nb) {
            const int col = nb * 16 + l15;
            v4f acc = {0.f, 0.f, 0.f, 0.f};
#pragma unroll
            for (int kc = 0; kc < 4; ++kc) {
                v8s bf = *(const v8s*)(w_lds + col * 136 + kc * 32 + quad * 8);
                acc = MFMA16(af[kc], bf, acc);
            }
            float bval = bias[col];
#pragma unroll
            for (int reg = 0; reg < 4; ++reg) {
                float val = acc[reg] + bval;
                if (m == 0) {
                    int lr = wave * 16 + quad * 4 + reg;
                    o_lds[lr * 136 + col] = f2bf(val * QSCALE);
                } else if (m == 1) {
                    int lr = wave * 16 + quad * 4 + reg;
                    o_lds[lr * 136 + col] = f2bf(val);
                } else {
                    int plr = wave * 16 + quadp * 4 + reg;   // fragment-order key
                    o_lds[col * 72 + plr] = f2bf(val);       // transpose for vF
                }
            }
        }
        __syncthreads();   // o_lds ready

        if (m == 0) {
#pragma unroll
            for (int it = 0; it < 4; ++it) {
                int id = it * 256 + tid;
                int r = id >> 4, c8 = id & 15;
                *(v8s*)(qo + (size_t)(rbase + r) * DD + c8 * 8) =
                    *(const v8s*)(o_lds + r * 136 + c8 * 8);
            }
        } else if (m == 1) {
            // kF[t][c=d-octet][key&31][8]: frag = o_lds[row r][d-octet c8]
#pragma unroll
            for (int it = 0; it < 4; ++it) {
                int id = it * 256 + tid;
                int r = id & 63, c8 = id >> 6;
                *(v8s*)(kF + (((t0 + (r >> 5)) * 16 + c8) * 32 + (r & 31)) * 8) =
                    *(const v8s*)(o_lds + r * 136 + c8 * 8);
            }
        } else {
            // vF[t][c=key-octet][d][8]: frag = o_lds[col d][key-octet c]
#pragma unroll
            for (int it = 0; it < 4; ++it) {
                int id = it * 256 + tid;
                int c = id >> 7, col = id & 127;
                *(v8s*)(vF + (((t0 + (c >> 2)) * 4 + (c & 3)) * 128 + col) * 8) =
                    *(const v8s*)(o_lds + col * 72 + c * 8);
            }
        }
    }
}

// ---------------- kernel 2: flash attention, NO-LDS main loop --------------
// 512 thr / 8 waves = 2 K-halves x 4 q-subsets (r6 decomposition), but K and
// V are consumed DIRECTLY global->register from the fragment-ordered kF/vF
// buffers: each frag load is one coalesced dwordx4 (two 512B runs/wave).
// No LDS, no GLDS, no ds_read, no barriers in the main loop -> the 2 waves/
// SIMD desync freely and MFMA/VALU/VMEM overlap (m114), removing the LDS
// pipe (r6: ~66% busy + 4.2M conflict-cyc) and the lockstep serialization.
// K double-buffered, V just-in-time (issued before QK, used after). b = bid&7
// pins each batch's 2MB K+V to one XCD's L2. Compiler manages waitcnts.
// Epilogue: r6-verified LDS half-merge (one __syncthreads).
#define NT 64             // 32-key tiles per half
__global__ __launch_bounds__(512, 2) void flash_kernel(
    const unsigned short* __restrict__ qp,
    const unsigned short* __restrict__ kF,
    const unsigned short* __restrict__ vF,
    float* __restrict__ outp)
{
    __shared__ __attribute__((aligned(16))) float mrg[16384];   // 64 KB
    __shared__ float xl[8 * 32];                                // 1 KB

    const int tid = threadIdx.x;
    const int wave = tid >> 6;
    const int lane = tid & 63;
    const int hi = lane >> 5;
    const int l31 = lane & 31;
    const int half = wave >> 2;    // K half: keys [half*2048, +2048)
    const int qs = wave & 3;       // query subset (32 q)
    const int bid = blockIdx.x;
    const int b = bid & 7;         // batch -> XCD pinning
    const int qt = bid >> 3;
    const int qbase = qt * 128;

    // ---- Q fragments (32 queries) ----
    const size_t qrow = (size_t)(b * SS + qbase + qs * 32 + l31) * DD;
    v8s qf[8];
#pragma unroll
    for (int kc = 0; kc < 8; ++kc)
        qf[kc] = *(const v8s*)(qp + qrow + kc * 16 + hi * 8);

    v16f o[4];
#pragma unroll
    for (int fg = 0; fg < 4; ++fg)
#pragma unroll
        for (int r = 0; r < 16; ++r) o[fg][r] = 0.f;
    float lp = 0.f;

    // ---- per-lane fragment pointers (shorts) ----
    // kF frag (t, kc): base + t*4096 + kc*512 + hi*256 + l31*8
    // vF frag (t, g, fg): base + t*4096 + g*2048 + hi*1024 + fg*256 + l31*8
    const size_t tbase = ((size_t)(b * 128 + half * 64)) * 4096;
    const unsigned short* kW = kF + tbase + hi * 256 + l31 * 8;
    const unsigned short* vW = vF + tbase + hi * 1024 + l31 * 8;

    v8s kfA[8], kfB[8], vf[8];
    auto loadK = [&](v8s (&kf)[8], int t) {
        const unsigned short* p = kW + (size_t)t * 4096;
#pragma unroll
        for (int kc = 0; kc < 8; ++kc)
            kf[kc] = *(const v8s*)(p + kc * 512);
    };
    auto loadV = [&](int t) {
        const unsigned short* p = vW + (size_t)t * 4096;
#pragma unroll
        for (int g = 0; g < 2; ++g)
#pragma unroll
            for (int fg = 0; fg < 4; ++fg)
                vf[g * 4 + fg] = *(const v8s*)(p + g * 2048 + fg * 256);
    };
    auto qkpv = [&](const v8s (&kf)[8]) {
        v16f s;
#pragma unroll
        for (int r = 0; r < 16; ++r) s[r] = 0.f;
#pragma unroll
        for (int kc = 0; kc < 8; ++kc)
            s = MFMA32(kf[kc], qf[kc], s);
        union { v8s v[2]; unsigned int u[8]; } P;
        float sum = 0.f;
#pragma unroll
        for (int g2 = 0; g2 < 2; ++g2) {
            float e[8];
#pragma unroll
            for (int r = 0; r < 8; ++r) e[r] = EXP2F(s[g2 * 8 + r]);
            sum += ((e[0] + e[1]) + (e[2] + e[3])) +
                   ((e[4] + e[5]) + (e[6] + e[7]));
#pragma unroll
            for (int m = 0; m < 4; ++m)
                P.u[g2 * 4 + m] = pk_bf16(e[2 * m], e[2 * m + 1]);
        }
        lp += sum;
#pragma unroll
        for (int g = 0; g < 2; ++g)
#pragma unroll
            for (int fg = 0; fg < 4; ++fg)
                o[fg] = MFMA32(P.v[g], vf[g * 4 + fg], o[fg]);
    };

    // ---- main loop: no barriers, no LDS; K dbuf + V JIT prefetch ----
    // (t = NT prefetch at the tail reads the adjacent frag buffer: in-bounds
    //  workspace, result unused.)
    loadK(kfA, 0);
#pragma unroll 1
    for (int t = 0; t < NT; t += 2) {
        loadV(t);
        loadK(kfB, t + 1);
        qkpv(kfA);
        loadV(t + 1);
        loadK(kfA, t + 2);
        qkpv(kfB);
    }

    // ---- epilogue: merge 2 halves in LDS (plain add: uniform scale) ----
    lp += __shfl_xor(lp, 32);
    if (hi == 0) xl[wave * 32 + l31] = lp;

    auto putO = [&](float* base) {
#pragma unroll
        for (int fg = 0; fg < 4; ++fg) {
            v4f* bp = (v4f*)(base + fg * 1024 + lane * 16);
#pragma unroll
            for (int c = 0; c < 4; ++c) {
                v4f tv = {o[fg][c * 4 + 0], o[fg][c * 4 + 1],
                          o[fg][c * 4 + 2], o[fg][c * 4 + 3]};
                bp[c ^ (lane & 3)] = tv;
            }
        }
    };
    auto addO = [&](const float* base) {
#pragma unroll
        for (int fg = 0; fg < 4; ++fg) {
            const v4f* bp = (const v4f*)(base + fg * 1024 + lane * 16);
#pragma unroll
            for (int c = 0; c < 4; ++c) {
                v4f tv = bp[c ^ (lane & 3)];
#pragma unroll
                for (int j = 0; j < 4; ++j) o[fg][c * 4 + j] += tv[j];
            }
        }
    };

    if (half == 1) putO(mrg + qs * 4096);
    __syncthreads();
    if (half == 0) {
        addO(mrg + qs * 4096);
        float ir[16];
#pragma unroll
        for (int r = 0; r < 16; ++r) {
            int qr = (r & 3) + 8 * (r >> 2) + 4 * hi;
            ir[r] = 1.0f / (xl[qs * 32 + qr] + xl[(4 + qs) * 32 + qr]);
        }
#pragma unroll
        for (int fg = 0; fg < 4; ++fg)
#pragma unroll
            for (int r = 0; r < 16; ++r) {
                int qr = (r & 3) + 8 * (r >> 2) + 4 * hi;
                outp[(size_t)(b * SS + qbase + qs * 32 + qr) * DD +
                     fg * 32 + l31] = o[fg][r] * ir[r];
            }
    }
}

extern "C" void kernel_launch(void* const* d_in, const int* in_sizes, int n_in,
                              void* d_out, int out_size, void* d_ws, size_t ws_size,
                              hipStream_t stream)
{
    const float* x  = (const float*)d_in[0];
    const float* Wq = (const float*)d_in[1];
    const float* bq = (const float*)d_in[2];
    const float* Wk = (const float*)d_in[3];
    const float* bk = (const float*)d_in[4];
    const float* Wv = (const float*)d_in[5];
    const float* bv = (const float*)d_in[6];
    float* out = (float*)d_out;

    unsigned short* Wt = (unsigned short*)d_ws;                  // 49152 shorts
    unsigned short* q  = Wt + 49152;
    unsigned short* kF = q + (size_t)BB * SS * DD;               // frag-ordered K
    unsigned short* vF = kF + (size_t)BB * SS * DD;              // frag-ordered V

    hipLaunchKernelGGL(prep_kernel, dim3(192), dim3(256), 0, stream,
                       Wq, Wk, Wv, Wt);
    hipLaunchKernelGGL(proj_kernel, dim3(BB * SS / 64), dim3(256), 0, stream,
                       x, Wt, bq, bk, bv, q, kF, vF);
    hipLaunchKernelGGL(flash_kernel, dim3(BB * SS / 128), dim3(512), 0, stream,
                       q, kF, vF, out);
}

// Round 10
// 167.939 us; speedup vs baseline: 1.5630x; 1.5630x over previous
//
#include <hip/hip_runtime.h>

#define BB 8
#define SS 4096
#define DD 128

typedef __attribute__((ext_vector_type(8))) short v8s;
typedef __attribute__((ext_vector_type(4))) float v4f;
typedef __attribute__((ext_vector_type(16))) float v16f;

__device__ __forceinline__ unsigned short f2bf(float f) {
    unsigned int u = __float_as_uint(f);
    u += 0x7fffu + ((u >> 16) & 1u);
    return (unsigned short)(u >> 16);
}
// pack bf16(a) | bf16(b)<<16, round-half-up, via v_perm
__device__ __forceinline__ unsigned int pk_bf16(float a, float b) {
    unsigned int ua = __float_as_uint(a) + 0x8000u;
    unsigned int ub = __float_as_uint(b) + 0x8000u;
    return __builtin_amdgcn_perm(ub, ua, 0x07060302u);
}

#if !defined(__HIP_DEVICE_COMPILE__)
#define MFMA16(a, b, c) (c)
#define MFMA32(a, b, c) (c)
#define GLDS16(g, l)
#define WAITVM(n)
#define WAITLGKM()
#define BAR()
#else
#define MFMA16(a, b, c) __builtin_amdgcn_mfma_f32_16x16x32_bf16((a), (b), (c), 0, 0, 0)
#define MFMA32(a, b, c) __builtin_amdgcn_mfma_f32_32x32x16_bf16((a), (b), (c), 0, 0, 0)
// async global->LDS DMA, 16B/lane, LDS dest = uniform base + lane*16
#define GLDS16(g, l)                                                         \
    __builtin_amdgcn_global_load_lds(                                        \
        (const __attribute__((address_space(1))) unsigned int*)(g),          \
        (__attribute__((address_space(3))) unsigned int*)(l), 16, 0, 0)
#define WAITVM(n) asm volatile("s_waitcnt vmcnt(" #n ")" ::: "memory")
#define WAITLGKM() asm volatile("s_waitcnt lgkmcnt(0)" ::: "memory")
#define BAR()                                                                \
    do {                                                                     \
        asm volatile("" ::: "memory");                                       \
        __builtin_amdgcn_s_barrier();                                        \
        __builtin_amdgcn_sched_barrier(0);                                   \
        asm volatile("" ::: "memory");                                       \
    } while (0)
#endif

#if !defined(__HIP_DEVICE_COMPILE__)
#define EXP2F(x) exp2f(x)
#elif __has_builtin(__builtin_amdgcn_exp2f)
#define EXP2F(x) __builtin_amdgcn_exp2f(x)
#else
#define EXP2F(x) exp2f(x)
#endif

// (1/sqrt(128)) * log2(e): softmax in 2^x domain (no max subtraction: scores
// in log2 domain ~N(0,~6^2), fp32 overflow needs >20 sigma; the uniform
// scale cancels exactly in O/l). Both K-halves share the scale -> merging
// partial O/l is a plain add.
#define QSCALE 0.12751743f

// ---------------- kernel 0: W transpose (r6-verified verbatim) -------------
__global__ __launch_bounds__(256) void prep_kernel(
    const float* __restrict__ Wq, const float* __restrict__ Wk,
    const float* __restrict__ Wv, unsigned short* __restrict__ Wt)
{
    int id = blockIdx.x * 256 + threadIdx.x;
    int w = id >> 14;
    int n = (id >> 7) & 127;
    int k = id & 127;
    const float* W = (w == 0) ? Wq : (w == 1) ? Wk : Wv;
    Wt[id] = f2bf(W[k * 128 + n]);
}

// ---------------- kernel 1: projections, ALL 3 matrices per block ----------
// r9-verified body (x + trig once for 3 matrices). Outputs:
//   q: natural [row][d]            (flash Q + K-GLDS path needs row-major)
//   k: natural [row][d]            (r8-verified store)
//   vF: MFMA-fragment order [t(32-key)][c=key-octet, quadp order][d][8]
//       (r9-verified store) -> flash loads V frags with coalesced dwordx4.
__global__ __launch_bounds__(256, 2) void proj_kernel(
    const float* __restrict__ x, const unsigned short* __restrict__ Wt,
    const float* __restrict__ bq, const float* __restrict__ bk,
    const float* __restrict__ bv,
    unsigned short* __restrict__ qo, unsigned short* __restrict__ ko,
    unsigned short* __restrict__ vF)
{
    __shared__ __attribute__((aligned(16))) unsigned short w_lds[128 * 136]; // 34816 B
    __shared__ __attribute__((aligned(16))) unsigned short o_lds[9216];      // 18432 B

    const int tid = threadIdx.x;
    const int wave = tid >> 6;
    const int lane = tid & 63;
    const int quad = lane >> 4;
    const int l15 = lane & 15;
    const int rbase = blockIdx.x * 64;

    const int flatrow = rbase + wave * 16 + l15;
    const int srow = flatrow & 4095;
    v8s af[4];
#pragma unroll
    for (int kc = 0; kc < 4; ++kc) {
        const int kbase = kc * 32 + quad * 8;
        const v4f* xp = (const v4f*)(x + (size_t)flatrow * DD + kbase);
        v4f x0 = xp[0], x1 = xp[1];
        float p[8];
#pragma unroll
        for (int j = 0; j < 8; j += 2) {
            float freq = __expf((float)(kbase + j) * -0.07195578415606394f);
            float arg = (float)srow * freq;
            p[j] = __sinf(arg);
            p[j + 1] = __cosf(arg);
        }
        v8s a;
#pragma unroll
        for (int j = 0; j < 4; ++j) a[j] = (short)f2bf(x0[j] + p[j]);
#pragma unroll
        for (int j = 0; j < 4; ++j) a[4 + j] = (short)f2bf(x1[j] + p[4 + j]);
        af[kc] = a;
    }

    const int quadp = ((quad & 1) << 1) | (quad >> 1);
    const int b0 = rbase >> 12, s0 = rbase & 4095;
    const size_t t0 = (size_t)b0 * 128 + (s0 >> 5);   // 32-key tile index

#pragma unroll 1
    for (int m = 0; m < 3; ++m) {
        const float* bias = (m == 0) ? bq : (m == 1) ? bk : bv;
        __syncthreads();   // previous m's users of w_lds/o_lds done
        const unsigned short* Wp = Wt + (m << 14);
#pragma unroll
        for (int it = 0; it < 8; ++it) {
            int id = it * 256 + tid;
            int n = id >> 4, c8 = id & 15;
            *(v8s*)(w_lds + n * 136 + c8 * 8) = *(const v8s*)(Wp + n * 128 + c8 * 8);
        }
        __syncthreads();   // w_lds ready

#pragma unroll
        for (int nb = 0; nb < 8; ++nb) {
            const int col = nb * 16 + l15;
            v4f acc = {0.f, 0.f, 0.f, 0.f};
#pragma unroll
            for (int kc = 0; kc < 4; ++kc) {
                v8s bf = *(const v8s*)(w_lds + col * 136 + kc * 32 + quad * 8);
                acc = MFMA16(af[kc], bf, acc);
            }
            float bval = bias[col];
#pragma unroll
            for (int reg = 0; reg < 4; ++reg) {
                float val = acc[reg] + bval;
                if (m == 0) {
                    int lr = wave * 16 + quad * 4 + reg;
                    o_lds[lr * 136 + col] = f2bf(val * QSCALE);
                } else if (m == 1) {
                    int lr = wave * 16 + quad * 4 + reg;
                    o_lds[lr * 136 + col] = f2bf(val);
                } else {
                    int plr = wave * 16 + quadp * 4 + reg;   // fragment-order key
                    o_lds[col * 72 + plr] = f2bf(val);       // transpose for vF
                }
            }
        }
        __syncthreads();   // o_lds ready

        if (m <= 1) {
            unsigned short* outp = (m == 0) ? qo : ko;
#pragma unroll
            for (int it = 0; it < 4; ++it) {
                int id = it * 256 + tid;
                int r = id >> 4, c8 = id & 15;
                *(v8s*)(outp + (size_t)(rbase + r) * DD + c8 * 8) =
                    *(const v8s*)(o_lds + r * 136 + c8 * 8);
            }
        } else {
            // vF[t][c=key-octet][d][8]: frag = o_lds[col d][key-octet c]
#pragma unroll
            for (int it = 0; it < 4; ++it) {
                int id = it * 256 + tid;
                int c = id >> 7, col = id & 127;
                *(v8s*)(vF + (((t0 + (c >> 2)) * 4 + (c & 3)) * 128 + col) * 8) =
                    *(const v8s*)(o_lds + col * 72 + c * 8);
            }
        }
    }
}

// ---------------- kernel 2: flash attention, hybrid K-LDS / V-direct -------
// 512 thr / 8 waves = 2 K-halves x 4 q-subsets (r6 decomposition).
// K: r6-verified GLDS->LDS pipeline (swizzled source, counted vmcnt) -- the
//    operand that needs broadcast + swizzle stays in LDS.
// V: direct global->register from r9-verified fragment-ordered vF, double-
//    buffered (X/Y), prefetch distance = one full 32-key phase (~1000 cyc
//    >> L2 latency) -- removes the V half of the LDS pipe (r6's binding
//    resource) at a TA cost that overlaps MFMA.
// vmcnt ledger (FIFO): steady state 20 outstanding = K-GLDS(4) + X(8) + Y(8);
// WAITVM(12) retires exactly one phase. l on VALU + shfl.
#define HKEYS 2048
#define NT 32             // 64-key tiles per half
__global__ __launch_bounds__(512, 2) void flash_kernel(
    const unsigned short* __restrict__ qp,
    const unsigned short* __restrict__ kp,
    const unsigned short* __restrict__ vF,
    float* __restrict__ outp)
{
    __shared__ __attribute__((aligned(16))) unsigned short k_lds[2][2][8192]; // 64 KB
    __shared__ float xl[8][32];                                               // 1 KB

    const int tid = threadIdx.x;
    const int wave = tid >> 6;
    const int lane = tid & 63;
    const int hi = lane >> 5;
    const int l31 = lane & 31;
    const int half = wave >> 2;    // K half: keys [half*2048, +2048)
    const int qs = wave & 3;       // query subset (32 q)
    const int wv = wave & 3;       // staging sub-wave within half cohort
    const int bid = blockIdx.x;
    const int b = bid & 7;         // batch -> XCD pinning
    const int qt = bid >> 3;
    const int qbase = qt * 128;

    // ---- Q fragments (32 queries) ----
    const size_t qrow = (size_t)(b * SS + qbase + qs * 32 + l31) * DD;
    v8s qf[8];
#pragma unroll
    for (int kc = 0; kc < 8; ++kc)
        qf[kc] = *(const v8s*)(qp + qrow + kc * 16 + hi * 8);

    v16f o[4];
#pragma unroll
    for (int fg = 0; fg < 4; ++fg)
#pragma unroll
        for (int r = 0; r < 16; ++r) o[fg][r] = 0.f;
    float lp = 0.f;

    // ---- K LDS read base (r6 verbatim) ----
    // K: row = sub*32+l31 (256 B rows), slot = (2kc+hi) ^ (l31&15)
    const int kro = half * 32768 + l31 * 256 + ((hi ^ (l31 & 15)) << 4);

    // ---- K GLDS per-lane pre-swizzled source (r6 verbatim) ----
    const int krow = wv * 4 + (lane >> 4);            // row&15, const over it
    const unsigned short* ksrc =
        kp + ((size_t)(b * SS + half * HKEYS) + krow) * DD +
        (((lane & 15) ^ krow) << 3);
    unsigned short* kd0 = &k_lds[half][0][wv * 512];  // wv*4 rows * 128

    // ---- V per-lane fragment pointer (r9 verbatim; u = 32-key tile idx) ----
    const size_t tbase = ((size_t)(b * 128 + half * 64)) * 4096;
    const unsigned short* vW = vF + tbase + hi * 1024 + l31 * 8;

    v8s X[8], Y[8];
    auto stage = [&](int p, int t) {
        unsigned short* kd = kd0 + p * 8192;
        const unsigned short* ks = ksrc + (size_t)t * 64 * DD;
#pragma unroll
        for (int it = 0; it < 4; ++it)
            GLDS16(ks + (size_t)it * 16 * DD, kd + it * 2048);
    };
    auto loadV = [&](v8s (&buf)[8], int u) {
        const unsigned short* p = vW + (size_t)u * 4096;
#pragma unroll
        for (int g = 0; g < 2; ++g)
#pragma unroll
            for (int fg = 0; fg < 4; ++fg)
                buf[g * 4 + fg] = *(const v8s*)(p + g * 2048 + fg * 256);
    };
    auto compute = [&](int p, int sub, const v8s (&buf)[8]) {
        const int ka = kro + p * 16384 + sub * 8192;
        v16f s;
#pragma unroll
        for (int r = 0; r < 16; ++r) s[r] = 0.f;
#pragma unroll
        for (int kc = 0; kc < 8; ++kc) {
            v8s af = *(const v8s*)((const char*)k_lds + (ka ^ (kc << 5)));
            s = MFMA32(af, qf[kc], s);
        }
        float e[16];
#pragma unroll
        for (int r = 0; r < 16; ++r) e[r] = EXP2F(s[r]);
        lp += (((e[0] + e[1]) + (e[2] + e[3])) + ((e[4] + e[5]) + (e[6] + e[7]))) +
              (((e[8] + e[9]) + (e[10] + e[11])) + ((e[12] + e[13]) + (e[14] + e[15])));
        union { v8s v[2]; unsigned int u[8]; } P;
#pragma unroll
        for (int g = 0; g < 2; ++g)
#pragma unroll
            for (int m = 0; m < 4; ++m)
                P.u[g * 4 + m] = pk_bf16(e[2 * m + 8 * g], e[2 * m + 8 * g + 1]);
#pragma unroll
        for (int g = 0; g < 2; ++g)
#pragma unroll
            for (int fg = 0; fg < 4; ++fg)
                o[fg] = MFMA32(P.v[g], buf[g * 4 + fg], o[fg]);
    };

    // ---- pipeline: 2 barriers per 64-key K tile; V prefetched 1 phase ahead
    stage(0, 0);          // 4 GLDS
    loadV(X, 0);          // 8 loads (tile 0, sub 0)
    loadV(Y, 1);          // 8 loads (tile 0, sub 1)   -> 20 outstanding
#pragma unroll 1
    for (int t = 0; t < NT; t += 2) {
        stage(1, t + 1);                 // +4 -> 24
        WAITVM(12);                      // K_t + X landed
        BAR();
        compute(0, 0, X);
        loadV(X, 2 * t + 2);             // +8 -> 20 (tile t+1, sub 0)
        WAITVM(12);                      // Y landed
        compute(0, 1, Y);
        loadV(Y, 2 * t + 3);             // +8 -> 20 (tile t+1, sub 1)
        WAITLGKM();
        BAR();                           // buf0 free for restage
        if (t + 2 < NT) {
            stage(0, t + 2);             // +4 -> 24
            WAITVM(12);                  // K_{t+1} + X landed
        } else {
            WAITVM(8);                   // K_{t+1} + X landed (20 -> 8)
        }
        BAR();
        compute(1, 0, X);
        if (t + 2 < NT) {
            loadV(X, 2 * t + 4);         // +8 (tile t+2, sub 0)
            WAITVM(12);                  // Y landed
        } else {
            WAITVM(0);                   // Y landed
        }
        compute(1, 1, Y);
        if (t + 2 < NT) loadV(Y, 2 * t + 5);   // +8 -> 20 invariant
        WAITLGKM();
        BAR();
    }

    // ---- epilogue: merge 2 halves in LDS (plain add: uniform scale) ----
    lp += __shfl_xor(lp, 32);
    if (hi == 0) xl[wave][l31] = lp;

    float* kf = (float*)&k_lds[0][0][0];   // 16384 floats: 4 regions of 4096

    auto putO = [&](float* base) {
#pragma unroll
        for (int fg = 0; fg < 4; ++fg) {
            v4f* bp = (v4f*)(base + fg * 1024 + lane * 16);
#pragma unroll
            for (int c = 0; c < 4; ++c) {
                v4f tv = {o[fg][c * 4 + 0], o[fg][c * 4 + 1],
                          o[fg][c * 4 + 2], o[fg][c * 4 + 3]};
                bp[c ^ (lane & 3)] = tv;
            }
        }
    };
    auto addO = [&](const float* base) {
#pragma unroll
        for (int fg = 0; fg < 4; ++fg) {
            const v4f* bp = (const v4f*)(base + fg * 1024 + lane * 16);
#pragma unroll
            for (int c = 0; c < 4; ++c) {
                v4f tv = bp[c ^ (lane & 3)];
#pragma unroll
                for (int j = 0; j < 4; ++j) o[fg][c * 4 + j] += tv[j];
            }
        }
    };

    if (half == 1) putO(kf + qs * 4096);
    __syncthreads();
    if (half == 0) {
        addO(kf + qs * 4096);
        float ir[16];
#pragma unroll
        for (int r = 0; r < 16; ++r) {
            int qr = (r & 3) + 8 * (r >> 2) + 4 * hi;
            ir[r] = 1.0f / (xl[qs][qr] + xl[4 + qs][qr]);
        }
#pragma unroll
        for (int fg = 0; fg < 4; ++fg)
#pragma unroll
            for (int r = 0; r < 16; ++r) {
                int qr = (r & 3) + 8 * (r >> 2) + 4 * hi;
                outp[(size_t)(b * SS + qbase + qs * 32 + qr) * DD +
                     fg * 32 + l31] = o[fg][r] * ir[r];
            }
    }
}

extern "C" void kernel_launch(void* const* d_in, const int* in_sizes, int n_in,
                              void* d_out, int out_size, void* d_ws, size_t ws_size,
                              hipStream_t stream)
{
    const float* x  = (const float*)d_in[0];
    const float* Wq = (const float*)d_in[1];
    const float* bq = (const float*)d_in[2];
    const float* Wk = (const float*)d_in[3];
    const float* bk = (const float*)d_in[4];
    const float* Wv = (const float*)d_in[5];
    const float* bv = (const float*)d_in[6];
    float* out = (float*)d_out;

    unsigned short* Wt = (unsigned short*)d_ws;                  // 49152 shorts
    unsigned short* q  = Wt + 49152;
    unsigned short* k  = q + (size_t)BB * SS * DD;               // natural K
    unsigned short* vF = k + (size_t)BB * SS * DD;               // frag-ordered V

    hipLaunchKernelGGL(prep_kernel, dim3(192), dim3(256), 0, stream,
                       Wq, Wk, Wv, Wt);
    hipLaunchKernelGGL(proj_kernel, dim3(BB * SS / 64), dim3(256), 0, stream,
                       x, Wt, bq, bk, bv, q, k, vF);
    hipLaunchKernelGGL(flash_kernel, dim3(BB * SS / 128), dim3(512), 0, stream,
                       q, k, vF, out);
}